// Round 1
// baseline (2342.328 us; speedup 1.0000x reference)
//
#include <hip/hip_runtime.h>
#include <cstddef>

// 3-layer tanh RNN, fused single kernel.
// B=8192, T=80, D=32, H=64. Block = 512 thr = 8 waves, lane = batch (64/block),
// wave w owns outputs j in [8w, 8w+8). Weights wave-uniform -> SGPR scalar loads.
// h state in LDS [layer][k][batch] (conflict-free: consecutive lanes -> consecutive banks).

__device__ __forceinline__ float fast_tanh(float a) {
  // robust at +-inf: exp(2a)->inf => 1, exp(2a)->0 => -1
  return 1.f - 2.f / (__expf(2.f * a) + 1.f);
}

__device__ __forceinline__ void rec_layer(
    const float* __restrict__ Wih, const float* __restrict__ Whh,
    const float* __restrict__ bih, const float* __restrict__ bhh,
    const float (&hin)[64][64],   // input activations (current t), read-only here
    float (&hrec)[64][64],        // this layer's state: read (t-1), then write (t)
    int jbase, int lane)
{
  float acc[8];
#pragma unroll
  for (int jj = 0; jj < 8; ++jj) acc[jj] = bih[jbase + jj] + bhh[jbase + jj];

  // input projection: acc[j] += sum_k Wih[j][k] * hin[k][lane]
#pragma unroll
  for (int kb = 0; kb < 64; kb += 16) {
    float hk[16];
#pragma unroll
    for (int i = 0; i < 16; ++i) hk[i] = hin[kb + i][lane];
#pragma unroll
    for (int jj = 0; jj < 8; ++jj) {
      const float* wr = Wih + (jbase + jj) * 64 + kb;   // wave-uniform addr -> s_load
#pragma unroll
      for (int i = 0; i < 16; ++i) acc[jj] += wr[i] * hk[i];
    }
  }
  // recurrence: acc[j] += sum_k Whh[j][k] * hrec[k][lane]  (state at t-1)
#pragma unroll
  for (int kb = 0; kb < 64; kb += 16) {
    float hk[16];
#pragma unroll
    for (int i = 0; i < 16; ++i) hk[i] = hrec[kb + i][lane];
#pragma unroll
    for (int jj = 0; jj < 8; ++jj) {
      const float* wr = Whh + (jbase + jj) * 64 + kb;
#pragma unroll
      for (int i = 0; i < 16; ++i) acc[jj] += wr[i] * hk[i];
    }
  }
  __syncthreads();   // all waves done READING hrec(t-1) before overwrite
#pragma unroll
  for (int jj = 0; jj < 8; ++jj) hrec[jbase + jj][lane] = fast_tanh(acc[jj]);
  __syncthreads();   // writes visible to all waves
}

__global__ __launch_bounds__(512, 2) void rnn3_fused(
    const float* __restrict__ x,
    const float* __restrict__ Wih0, const float* __restrict__ Whh0,
    const float* __restrict__ bih0, const float* __restrict__ bhh0,
    const float* __restrict__ Wih1, const float* __restrict__ Whh1,
    const float* __restrict__ bih1, const float* __restrict__ bhh1,
    const float* __restrict__ Wih2, const float* __restrict__ Whh2,
    const float* __restrict__ bih2, const float* __restrict__ bhh2,
    const float* __restrict__ Wfc, const float* __restrict__ bfc,
    float* __restrict__ out)
{
  __shared__ float hs[3][64][64];   // [layer][unit k][batch lane], 48 KiB

  const int lane  = threadIdx.x & 63;
  const int wv    = __builtin_amdgcn_readfirstlane((int)(threadIdx.x >> 6));
  const int jbase = wv * 8;
  const int b     = (int)blockIdx.x * 64 + lane;

  for (int i = threadIdx.x; i < 3 * 64 * 64; i += 512) (&hs[0][0][0])[i] = 0.f;
  __syncthreads();

  const float* xb = x + (size_t)b * 80 * 32;

  for (int t = 0; t < 80; ++t) {
    // ---------- layer 0: pre = x_t @ Wih0^T + b + h0 @ Whh0^T ----------
    float acc[8];
    const float4* xp = (const float4*)(xb + t * 32);
    float4 xr[8];
#pragma unroll
    for (int i = 0; i < 8; ++i) xr[i] = xp[i];   // 32 floats of x[b][t][:]

#pragma unroll
    for (int jj = 0; jj < 8; ++jj) {
      const int j = jbase + jj;
      float a = bih0[j] + bhh0[j];
      const float4* w = (const float4*)(Wih0 + j * 32);   // wave-uniform
#pragma unroll
      for (int i = 0; i < 8; ++i) {
        const float4 w4 = w[i];
        a += w4.x * xr[i].x; a += w4.y * xr[i].y;
        a += w4.z * xr[i].z; a += w4.w * xr[i].w;
      }
      acc[jj] = a;
    }
#pragma unroll
    for (int kb = 0; kb < 64; kb += 16) {
      float hk[16];
#pragma unroll
      for (int i = 0; i < 16; ++i) hk[i] = hs[0][kb + i][lane];
#pragma unroll
      for (int jj = 0; jj < 8; ++jj) {
        const float* wr = Whh0 + (jbase + jj) * 64 + kb;
#pragma unroll
        for (int i = 0; i < 16; ++i) acc[jj] += wr[i] * hk[i];
      }
    }
    __syncthreads();
#pragma unroll
    for (int jj = 0; jj < 8; ++jj) hs[0][jbase + jj][lane] = fast_tanh(acc[jj]);
    __syncthreads();

    // ---------- layers 1, 2 ----------
    rec_layer(Wih1, Whh1, bih1, bhh1, hs[0], hs[1], jbase, lane);
    rec_layer(Wih2, Whh2, bih2, bhh2, hs[1], hs[2], jbase, lane);
  }

  // ---------- FC head: out[b] = h2_final . Wfc + bfc ----------
  if (wv == 0) {
    float a = bfc[0];
#pragma unroll
    for (int k = 0; k < 64; ++k) a += Wfc[k] * hs[2][k][lane];
    out[b] = a;
  }
}

extern "C" void kernel_launch(void* const* d_in, const int* in_sizes, int n_in,
                              void* d_out, int out_size, void* d_ws, size_t ws_size,
                              hipStream_t stream) {
  const float* x    = (const float*)d_in[0];
  const float* Wih0 = (const float*)d_in[1];
  const float* Whh0 = (const float*)d_in[2];
  const float* bih0 = (const float*)d_in[3];
  const float* bhh0 = (const float*)d_in[4];
  const float* Wih1 = (const float*)d_in[5];
  const float* Whh1 = (const float*)d_in[6];
  const float* bih1 = (const float*)d_in[7];
  const float* bhh1 = (const float*)d_in[8];
  const float* Wih2 = (const float*)d_in[9];
  const float* Whh2 = (const float*)d_in[10];
  const float* bih2 = (const float*)d_in[11];
  const float* bhh2 = (const float*)d_in[12];
  const float* Wfc  = (const float*)d_in[13];
  const float* bfc  = (const float*)d_in[14];

  rnn3_fused<<<dim3(8192 / 64), dim3(512), 0, stream>>>(
      x, Wih0, Whh0, bih0, bhh0, Wih1, Whh1, bih1, bhh1,
      Wih2, Whh2, bih2, bhh2, Wfc, bfc, (float*)d_out);
}

// Round 2
// 278.793 us; speedup vs baseline: 8.4017x; 8.4017x over previous
//
#include <hip/hip_runtime.h>
#include <cstddef>

// 3-layer tanh RNN (B=8192, T=80, D=32, H=64) fused into one kernel, MFMA-based.
//
// Orientation: D[j][b] = sum_k W[j][k] * h[b][k]  ->  A = weights, B = activations.
//   A-frag (16x16x32): lane holds A[m = lane&15][k = (lane>>4)*8 + i]  (weights, in regs)
//   B-frag:            lane holds B[k = (lane>>4)*8 + i][n = lane&15]  (activations)
//   C/D:               lane holds D[row = (lane>>4)*4 + r][col = lane&15]
// Wave = 16 batch rows (the n dim), fully independent: no __syncthreads anywhere.
// D-layout -> B-layout transform between layers goes through wave-private LDS
// (h[b][j] bf16, row stride 72 to break bank alignment): 4x ds_write_b64 + 2x ds_read_b128.
// All weights live in VGPRs as bf16 A-frags (~176 VGPRs), loaded once before the t-loop.
// Biases pre-scaled by 2*log2(e) and folded into the exp2 fma of tanh; acc init is a
// constant zero C operand (no per-t cost).
// rec-state reuse: layer l's recurrent B-frag at t == layer (l+1)'s input B-frag at t-1
// (register copy); layer 2's comes from re-reading its LDS buffer (zeroed at start).

typedef __attribute__((ext_vector_type(8))) short s16x8;
typedef __attribute__((ext_vector_type(4))) short s16x4;
typedef __attribute__((ext_vector_type(4))) float fx4;

#define MFMA16(A, B, C) __builtin_amdgcn_mfma_f32_16x16x32_bf16((A), (B), (C), 0, 0, 0)

#if __has_builtin(__builtin_amdgcn_exp2f)
#define EXP2F(x) __builtin_amdgcn_exp2f(x)
#else
#define EXP2F(x) exp2f(x)
#endif
#if __has_builtin(__builtin_amdgcn_rcpf)
#define RCPF(x) __builtin_amdgcn_rcpf(x)
#else
#define RCPF(x) (1.0f / (x))
#endif

static constexpr float K2LOG2E = 2.8853900817779268f;  // 2*log2(e)

__device__ __forceinline__ short f2bf(float f) {  // RNE float->bf16
  union { float f; unsigned u; } v; v.f = f;
  unsigned r = v.u + 0x7FFFu + ((v.u >> 16) & 1u);
  return (short)(r >> 16);
}
__device__ __forceinline__ float bf2f(short s) {
  union { unsigned u; float f; } v; v.u = ((unsigned)(unsigned short)s) << 16;
  return v.f;
}

// Load one A-operand weight fragment from a row-major fp32 matrix.
__device__ __forceinline__ s16x8 wfragA(const float* W, int ncols, int row, int col0) {
  const float* p = W + row * ncols + col0;
  s16x8 r;
#pragma unroll
  for (int i = 0; i < 8; ++i) r[i] = f2bf(p[i]);
  return r;
}

// tanh(acc + bias) with bias pre-scaled by 2*log2(e), then pack to bf16 and store
// 4 values (one D-tile row group) per ds_write_b64 into h[b][j] (stride 72 shorts).
__device__ __forceinline__ void act_store(const fx4* acc, const float* bsc,
                                          short* hL, int m15, int q) {
  short* row = hL + m15 * 72 + 4 * q;
#pragma unroll
  for (int mb = 0; mb < 4; ++mb) {
    s16x4 v;
#pragma unroll
    for (int r = 0; r < 4; ++r) {
      float e = EXP2F(__builtin_fmaf(acc[mb][r], K2LOG2E, bsc[mb * 4 + r]));
      float h = 1.f - 2.f * RCPF(e + 1.f);
      v[r] = f2bf(h);
    }
    *(s16x4*)(row + 16 * mb) = v;
  }
}

__device__ __forceinline__ s16x8 ld_bfrag(const short* hL, int m15, int q, int kf) {
  return *(const s16x8*)(hL + m15 * 72 + kf * 32 + q * 8);
}

__global__ __launch_bounds__(128, 1) void rnn3_mfma(
    const float* __restrict__ x,
    const float* __restrict__ Wih0, const float* __restrict__ Whh0,
    const float* __restrict__ bih0, const float* __restrict__ bhh0,
    const float* __restrict__ Wih1, const float* __restrict__ Whh1,
    const float* __restrict__ bih1, const float* __restrict__ bhh1,
    const float* __restrict__ Wih2, const float* __restrict__ Whh2,
    const float* __restrict__ bih2, const float* __restrict__ bhh2,
    const float* __restrict__ Wfc, const float* __restrict__ bfc,
    float* __restrict__ out)
{
  __shared__ __align__(16) short hbuf[2][3][16][72];  // [wave][layer][b][j], 13.5 KiB

  const int tid = threadIdx.x;
  const int wv  = tid >> 6;
  const int ln  = tid & 63;
  const int q   = ln >> 4;
  const int m15 = ln & 15;
  const int bbase = (int)blockIdx.x * 32 + wv * 16;

  short* h0 = &hbuf[wv][0][0][0];
  short* h1 = &hbuf[wv][1][0][0];
  short* h2 = &hbuf[wv][2][0][0];

  // zero h2 (it is read at t=0 before ever being written)
  for (int i = ln; i < 16 * 72; i += 64) h2[i] = 0;

  // ---------------- weight fragments (held in VGPRs for the whole kernel) ----------
  s16x8 wA_ih0[4], wA_hh0[4][2], wA_ih1[4][2], wA_hh1[4][2], wA_ih2[4][2], wA_hh2[4][2];
#pragma unroll
  for (int mb = 0; mb < 4; ++mb) {
    const int row = 16 * mb + m15;
    wA_ih0[mb] = wfragA(Wih0, 32, row, 8 * q);
#pragma unroll
    for (int kf = 0; kf < 2; ++kf) {
      const int c = 32 * kf + 8 * q;
      wA_hh0[mb][kf] = wfragA(Whh0, 64, row, c);
      wA_ih1[mb][kf] = wfragA(Wih1, 64, row, c);
      wA_hh1[mb][kf] = wfragA(Whh1, 64, row, c);
      wA_ih2[mb][kf] = wfragA(Wih2, 64, row, c);
      wA_hh2[mb][kf] = wfragA(Whh2, 64, row, c);
    }
  }

  // ---------------- biases, pre-scaled by 2*log2(e); j = 16*mb + 4*q + r -----------
  float bsc0[16], bsc1[16], bsc2[16];
#pragma unroll
  for (int mb = 0; mb < 4; ++mb)
#pragma unroll
    for (int r = 0; r < 4; ++r) {
      const int j = 16 * mb + 4 * q + r;
      bsc0[mb * 4 + r] = (bih0[j] + bhh0[j]) * K2LOG2E;
      bsc1[mb * 4 + r] = (bih1[j] + bhh1[j]) * K2LOG2E;
      bsc2[mb * 4 + r] = (bih2[j] + bhh2[j]) * K2LOG2E;
    }

  const fx4 zero4 = {0.f, 0.f, 0.f, 0.f};

  // recurrent-state B-frags at t-1 (zero-initial state)
  s16x8 rec0[2], rec1[2];
#pragma unroll
  for (int kf = 0; kf < 2; ++kf) {
    rec0[kf] = (s16x8){0, 0, 0, 0, 0, 0, 0, 0};
    rec1[kf] = (s16x8){0, 0, 0, 0, 0, 0, 0, 0};
  }

  // x B-frag source: lane reads x[bbase+m15][t][8q .. 8q+7], prefetched one t ahead
  const float* xr = x + (size_t)(bbase + m15) * (80 * 32) + 8 * q;
  fx4 xc0 = *(const fx4*)(xr);
  fx4 xc1 = *(const fx4*)(xr + 4);

  for (int t = 0; t < 80; ++t) {
    // prefetch x(t+1)
    fx4 xn0 = xc0, xn1 = xc1;
    if (t < 79) {
      xn0 = *(const fx4*)(xr + (t + 1) * 32);
      xn1 = *(const fx4*)(xr + (t + 1) * 32 + 4);
    }
    s16x8 xf;
#pragma unroll
    for (int i = 0; i < 4; ++i) { xf[i] = f2bf(xc0[i]); xf[4 + i] = f2bf(xc1[i]); }

    // ---------------- layer 0: D = Wih0 * x  +  Whh0 * h0(t-1) ----------------
    fx4 acc[4];
#pragma unroll
    for (int mb = 0; mb < 4; ++mb) acc[mb] = MFMA16(wA_ih0[mb], xf, zero4);
#pragma unroll
    for (int mb = 0; mb < 4; ++mb) acc[mb] = MFMA16(wA_hh0[mb][0], rec0[0], acc[mb]);
#pragma unroll
    for (int mb = 0; mb < 4; ++mb) acc[mb] = MFMA16(wA_hh0[mb][1], rec0[1], acc[mb]);
    act_store(acc, bsc0, h0, m15, q);

    // layer-2 recurrent state h2(t-1): issue the LDS read early (used below)
    s16x8 r2a = ld_bfrag(h2, m15, q, 0);
    s16x8 r2b = ld_bfrag(h2, m15, q, 1);

    // ---------------- layer 1: D = Wih1 * h0(t) + Whh1 * h1(t-1) ----------------
    s16x8 in0 = ld_bfrag(h0, m15, q, 0);
    s16x8 in1 = ld_bfrag(h0, m15, q, 1);
#pragma unroll
    for (int mb = 0; mb < 4; ++mb) acc[mb] = MFMA16(wA_ih1[mb][0], in0, zero4);
#pragma unroll
    for (int mb = 0; mb < 4; ++mb) acc[mb] = MFMA16(wA_ih1[mb][1], in1, acc[mb]);
#pragma unroll
    for (int mb = 0; mb < 4; ++mb) acc[mb] = MFMA16(wA_hh1[mb][0], rec1[0], acc[mb]);
#pragma unroll
    for (int mb = 0; mb < 4; ++mb) acc[mb] = MFMA16(wA_hh1[mb][1], rec1[1], acc[mb]);
    act_store(acc, bsc1, h1, m15, q);
    rec0[0] = in0; rec0[1] = in1;  // h0(t) becomes layer-0 rec state for t+1

    // ---------------- layer 2: D = Wih2 * h1(t) + Whh2 * h2(t-1) ----------------
    s16x8 j0 = ld_bfrag(h1, m15, q, 0);
    s16x8 j1 = ld_bfrag(h1, m15, q, 1);
#pragma unroll
    for (int mb = 0; mb < 4; ++mb) acc[mb] = MFMA16(wA_ih2[mb][0], j0, zero4);
#pragma unroll
    for (int mb = 0; mb < 4; ++mb) acc[mb] = MFMA16(wA_ih2[mb][1], j1, acc[mb]);
#pragma unroll
    for (int mb = 0; mb < 4; ++mb) acc[mb] = MFMA16(wA_hh2[mb][0], r2a, acc[mb]);
#pragma unroll
    for (int mb = 0; mb < 4; ++mb) acc[mb] = MFMA16(wA_hh2[mb][1], r2b, acc[mb]);
    act_store(acc, bsc2, h2, m15, q);
    rec1[0] = j0; rec1[1] = j1;    // h1(t) becomes layer-1 rec state for t+1

    xc0 = xn0; xc1 = xn1;
  }

  // ---------------- FC head: out[b] = h2(T-1) . Wfc + bfc ----------------
  s16x8 f0 = ld_bfrag(h2, m15, q, 0);
  s16x8 f1 = ld_bfrag(h2, m15, q, 1);
  float s = 0.f;
#pragma unroll
  for (int i = 0; i < 8; ++i) s += bf2f(f0[i]) * Wfc[8 * q + i];
#pragma unroll
  for (int i = 0; i < 8; ++i) s += bf2f(f1[i]) * Wfc[32 + 8 * q + i];
  s += __shfl_xor(s, 16, 64);
  s += __shfl_xor(s, 32, 64);
  if (ln < 16) out[bbase + ln] = s + bfc[0];
}

extern "C" void kernel_launch(void* const* d_in, const int* in_sizes, int n_in,
                              void* d_out, int out_size, void* d_ws, size_t ws_size,
                              hipStream_t stream) {
  const float* x    = (const float*)d_in[0];
  const float* Wih0 = (const float*)d_in[1];
  const float* Whh0 = (const float*)d_in[2];
  const float* bih0 = (const float*)d_in[3];
  const float* bhh0 = (const float*)d_in[4];
  const float* Wih1 = (const float*)d_in[5];
  const float* Whh1 = (const float*)d_in[6];
  const float* bih1 = (const float*)d_in[7];
  const float* bhh1 = (const float*)d_in[8];
  const float* Wih2 = (const float*)d_in[9];
  const float* Whh2 = (const float*)d_in[10];
  const float* bih2 = (const float*)d_in[11];
  const float* bhh2 = (const float*)d_in[12];
  const float* Wfc  = (const float*)d_in[13];
  const float* bfc  = (const float*)d_in[14];

  // 256 blocks x 128 threads = 512 independent waves, 16 batch rows each.
  rnn3_mfma<<<dim3(256), dim3(128), 0, stream>>>(
      x, Wih0, Whh0, bih0, bhh0, Wih1, Whh1, bih1, bhh1,
      Wih2, Whh2, bih2, bhh2, Wfc, bfc, (float*)d_out);
}

// Round 3
// 202.837 us; speedup vs baseline: 11.5479x; 1.3745x over previous
//
#include <hip/hip_runtime.h>
#include <hip/hip_bf16.h>
#include <cstddef>

// 3-layer tanh RNN (B=8192, T=80, D=32, H=64), fused, MFMA, j-split 4 ways.
//
// Block = 256 thr = 4 waves, owns 16 batch rows. Wave w computes output units
// j in [16w, 16w+16) via 16x16x32 bf16 MFMA (A = weights in VGPRs, B = activations).
//   A-frag: lane holds A[m=lane&15][k=8*(lane>>4)+i]
//   B-frag: lane holds B[k=8*(lane>>4)+i][n=lane&15]
//   C/D:    lane holds D[row=4*(lane>>4)+r][col=lane&15]      (verified in R2)
// Hidden state flows through LDS hb[layer][b][j] (stride 72 shorts), 3 barriers/t.
// Register carries: layer-(l+1)'s input read IS layer-l's next-t recurrent frag;
// h2's next-t frag is prefetched right after barrier-2 (a full layer of slack).
// x(t+1) prefetch issued right after barrier-0 so the vmcnt(0)-before-barrier
// drain lands a layer later. t=0 recurrent state = register zeros (no LDS init).

typedef __attribute__((ext_vector_type(8))) short s16x8;
typedef __attribute__((ext_vector_type(4))) short s16x4;
typedef __attribute__((ext_vector_type(4))) float fx4;

#define MFMA16(A, B, C) __builtin_amdgcn_mfma_f32_16x16x32_bf16((A), (B), (C), 0, 0, 0)

#if __has_builtin(__builtin_amdgcn_exp2f)
#define EXP2F(x) __builtin_amdgcn_exp2f(x)
#else
#define EXP2F(x) exp2f(x)
#endif
#if __has_builtin(__builtin_amdgcn_rcpf)
#define RCPF(x) __builtin_amdgcn_rcpf(x)
#else
#define RCPF(x) (1.0f / (x))
#endif

static constexpr float K2LOG2E = 2.8853900817779268f;  // 2*log2(e)

__device__ __forceinline__ short f2bf(float f) {  // RNE float->bf16 (weights, one-time)
  union { float f; unsigned u; } v; v.f = f;
  unsigned r = v.u + 0x7FFFu + ((v.u >> 16) & 1u);
  return (short)(r >> 16);
}
__device__ __forceinline__ float bf2f(short s) {
  union { unsigned u; float f; } v; v.u = ((unsigned)(unsigned short)s) << 16;
  return v.f;
}
__device__ __forceinline__ unsigned pk2bf(float a, float b) {  // v_cvt_pk_bf16_f32
  float2 t; t.x = a; t.y = b;
  union { __hip_bfloat162 h; unsigned u; } c;
  c.h = __float22bfloat162_rn(t);
  return c.u;
}

__device__ __forceinline__ s16x8 wfragA(const float* W, int ncols, int row, int col0) {
  const float* p = W + row * ncols + col0;
  s16x8 r;
#pragma unroll
  for (int i = 0; i < 8; ++i) r[i] = f2bf(p[i]);
  return r;
}

// tanh(acc + bias) with bias pre-scaled by 2*log2(e); pack 4 bf16, one ds_write_b64.
__device__ __forceinline__ void act_store(fx4 acc, const float* bsc, short* wp) {
  float h[4];
#pragma unroll
  for (int r = 0; r < 4; ++r) {
    float e = EXP2F(__builtin_fmaf(acc[r], K2LOG2E, bsc[r]));
    h[r] = 1.f - 2.f * RCPF(e + 1.f);
  }
  union { unsigned u[2]; s16x4 v; } p;
  p.u[0] = pk2bf(h[0], h[1]);
  p.u[1] = pk2bf(h[2], h[3]);
  *(s16x4*)wp = p.v;
}

__global__ __launch_bounds__(256, 2) void rnn3_mfma4(
    const float* __restrict__ x,
    const float* __restrict__ Wih0, const float* __restrict__ Whh0,
    const float* __restrict__ bih0, const float* __restrict__ bhh0,
    const float* __restrict__ Wih1, const float* __restrict__ Whh1,
    const float* __restrict__ bih1, const float* __restrict__ bhh1,
    const float* __restrict__ Wih2, const float* __restrict__ Whh2,
    const float* __restrict__ bih2, const float* __restrict__ bhh2,
    const float* __restrict__ Wfc, const float* __restrict__ bfc,
    float* __restrict__ out)
{
  __shared__ __align__(16) short hb[3][16][72];  // [layer][batch][j], 6912 B

  const int tid = threadIdx.x;
  const int wv  = tid >> 6;
  const int ln  = tid & 63;
  const int q   = ln >> 4;
  const int m15 = ln & 15;
  const int bbase = (int)blockIdx.x * 16;

  // ---------- weight A-fragments (VGPR-resident; rows j = 16*wv + m15) ----------
  const int arow = 16 * wv + m15;
  s16x8 wih0 = wfragA(Wih0, 32, arow, 8 * q);
  s16x8 whh0[2], wih1[2], whh1[2], wih2[2], whh2[2];
#pragma unroll
  for (int kf = 0; kf < 2; ++kf) {
    const int c = 32 * kf + 8 * q;
    whh0[kf] = wfragA(Whh0, 64, arow, c);
    wih1[kf] = wfragA(Wih1, 64, arow, c);
    whh1[kf] = wfragA(Whh1, 64, arow, c);
    wih2[kf] = wfragA(Wih2, 64, arow, c);
    whh2[kf] = wfragA(Whh2, 64, arow, c);
  }

  // ---------- biases, pre-scaled by 2*log2(e); lane's j = 16*wv + 4*q + r ----------
  float b0[4], b1[4], b2[4];
#pragma unroll
  for (int r = 0; r < 4; ++r) {
    const int j = 16 * wv + 4 * q + r;
    b0[r] = (bih0[j] + bhh0[j]) * K2LOG2E;
    b1[r] = (bih1[j] + bhh1[j]) * K2LOG2E;
    b2[r] = (bih2[j] + bhh2[j]) * K2LOG2E;
  }

  const fx4 z4 = {0.f, 0.f, 0.f, 0.f};
  const s16x8 z8 = {0, 0, 0, 0, 0, 0, 0, 0};
  s16x8 rec0a = z8, rec0b = z8, rec1a = z8, rec1b = z8, rec2a = z8, rec2b = z8;

  // LDS pointers for this lane
  short* wr0 = &hb[0][m15][16 * wv + 4 * q];
  short* wr1 = &hb[1][m15][16 * wv + 4 * q];
  short* wr2 = &hb[2][m15][16 * wv + 4 * q];
  const short* rd0 = &hb[0][m15][8 * q];
  const short* rd1 = &hb[1][m15][8 * q];
  const short* rd2 = &hb[2][m15][8 * q];

  // x source: lane reads x[bbase+m15][t][8q .. 8q+7]
  const float* xr = x + (size_t)(bbase + m15) * (80 * 32) + 8 * q;
  fx4 xc0 = *(const fx4*)(xr);
  fx4 xc1 = *(const fx4*)(xr + 4);

  for (int t = 0; t < 80; ++t) {
    // pack x(t) to bf16 B-frag
    union { unsigned u[4]; s16x8 v; } xp;
    xp.u[0] = pk2bf(xc0[0], xc0[1]); xp.u[1] = pk2bf(xc0[2], xc0[3]);
    xp.u[2] = pk2bf(xc1[0], xc1[1]); xp.u[3] = pk2bf(xc1[2], xc1[3]);

    // ---------------- layer 0 ----------------
    fx4 aA = MFMA16(wih0, xp.v, z4);
    fx4 aB = MFMA16(whh0[0], rec0a, z4);
    aB = MFMA16(whh0[1], rec0b, aB);
    act_store(aA + aB, b0, wr0);
    __syncthreads();                      // barrier 0: h0(t) visible

    // x(t+1) prefetch — issued here so the vmcnt drain lands at barrier 1
    const int tn = (t < 79) ? t + 1 : 79;
    fx4 xn0 = *(const fx4*)(xr + tn * 32);
    fx4 xn1 = *(const fx4*)(xr + tn * 32 + 4);

    // ---------------- layer 1 ----------------
    s16x8 in0 = *(const s16x8*)(rd0);
    s16x8 in1 = *(const s16x8*)(rd0 + 32);
    aA = MFMA16(whh1[0], rec1a, z4);      // independent of the in-read
    aA = MFMA16(whh1[1], rec1b, aA);
    aB = MFMA16(wih1[0], in0, z4);
    aB = MFMA16(wih1[1], in1, aB);
    act_store(aA + aB, b1, wr1);
    __syncthreads();                      // barrier 1: h1(t) visible
    rec0a = in0; rec0b = in1;             // h0(t) -> layer-0 rec for t+1

    // ---------------- layer 2 ----------------
    s16x8 j0 = *(const s16x8*)(rd1);
    s16x8 j1 = *(const s16x8*)(rd1 + 32);
    aA = MFMA16(whh2[0], rec2a, z4);
    aA = MFMA16(whh2[1], rec2b, aA);
    aB = MFMA16(wih2[0], j0, z4);
    aB = MFMA16(wih2[1], j1, aB);
    act_store(aA + aB, b2, wr2);
    __syncthreads();                      // barrier 2: h2(t) visible
    rec1a = j0; rec1b = j1;               // h1(t) -> layer-1 rec for t+1
    rec2a = *(const s16x8*)(rd2);         // h2(t) -> layer-2 rec for t+1
    rec2b = *(const s16x8*)(rd2 + 32);    // (full layer-0 of slack to complete)

    xc0 = xn0; xc1 = xn1;
  }

  // ---------- FC head: h2(79) already in rec2a/rec2b ----------
  float s = 0.f;
#pragma unroll
  for (int i = 0; i < 8; ++i) s += bf2f(rec2a[i]) * Wfc[8 * q + i];
#pragma unroll
  for (int i = 0; i < 8; ++i) s += bf2f(rec2b[i]) * Wfc[32 + 8 * q + i];
  s += __shfl_xor(s, 16, 64);
  s += __shfl_xor(s, 32, 64);
  if (wv == 0 && ln < 16) out[bbase + ln] = s + bfc[0];
}

extern "C" void kernel_launch(void* const* d_in, const int* in_sizes, int n_in,
                              void* d_out, int out_size, void* d_ws, size_t ws_size,
                              hipStream_t stream) {
  const float* x    = (const float*)d_in[0];
  const float* Wih0 = (const float*)d_in[1];
  const float* Whh0 = (const float*)d_in[2];
  const float* bih0 = (const float*)d_in[3];
  const float* bhh0 = (const float*)d_in[4];
  const float* Wih1 = (const float*)d_in[5];
  const float* Whh1 = (const float*)d_in[6];
  const float* bih1 = (const float*)d_in[7];
  const float* bhh1 = (const float*)d_in[8];
  const float* Wih2 = (const float*)d_in[9];
  const float* Whh2 = (const float*)d_in[10];
  const float* bih2 = (const float*)d_in[11];
  const float* bhh2 = (const float*)d_in[12];
  const float* Wfc  = (const float*)d_in[13];
  const float* bfc  = (const float*)d_in[14];

  // 512 blocks x 256 thr = 2048 waves = 2 waves/SIMD across all 1024 SIMDs.
  rnn3_mfma4<<<dim3(512), dim3(256), 0, stream>>>(
      x, Wih0, Whh0, bih0, bhh0, Wih1, Whh1, bih1, bhh1,
      Wih2, Whh2, bih2, bhh2, Wfc, bfc, (float*)d_out);
}

// Round 4
// 196.194 us; speedup vs baseline: 11.9389x; 1.0339x over previous
//
#include <hip/hip_runtime.h>
#include <hip/hip_bf16.h>
#include <cstddef>

// 3-layer tanh RNN (B=8192, T=80, D=32, H=64), fused, MFMA, SYSTOLIC LAYER PIPELINE.
//
// Block = 192 thr = 3 waves, owns 16 batch rows. Wave wv computes LAYER wv for all
// 64 output units, skewed in time: at tick tau, wave wv computes h_wv(t = tau - wv).
// One __syncthreads per tick (82 ticks) instead of 3 per t (240) — the three layers'
// [ds_read -> MFMA -> tanh -> ds_write] latencies now overlap across waves instead of
// summing on one critical path.
//
// MFMA 16x16x32 bf16, A = weights (VGPR-resident), B = activations:
//   A-frag: lane holds A[m=lane&15][k=8*(lane>>4)+i]
//   B-frag: lane holds B[k=8*(lane>>4)+i][n=lane&15]
//   C/D:    lane holds D[row=4*(lane>>4)+r][col=lane&15]      (verified R2/R3)
// h exchange: hb[layer][parity=t&1][batch][j] (stride 72 shorts). Writer: 4x
// ds_write_b64; reader: 2x ds_read_b128. Own-recurrence transpose is read back
// IMMEDIATELY after the write (same-wave DS ordering => RAW safe, pre-barrier),
// so after the barrier only the upstream read is on the critical path, and the
// MFMA chain starts with the (register-ready) Whh*rec terms to hide it.
// t=0 recurrent state = register zeros; upstream reads only occur when valid.

typedef __attribute__((ext_vector_type(8))) short s16x8;
typedef __attribute__((ext_vector_type(4))) short s16x4;
typedef __attribute__((ext_vector_type(4))) float fx4;

#define MFMA16(A, B, C) __builtin_amdgcn_mfma_f32_16x16x32_bf16((A), (B), (C), 0, 0, 0)

#if __has_builtin(__builtin_amdgcn_exp2f)
#define EXP2F(x) __builtin_amdgcn_exp2f(x)
#else
#define EXP2F(x) exp2f(x)
#endif
#if __has_builtin(__builtin_amdgcn_rcpf)
#define RCPF(x) __builtin_amdgcn_rcpf(x)
#else
#define RCPF(x) (1.0f / (x))
#endif

static constexpr float K2LOG2E = 2.8853900817779268f;  // 2*log2(e)

__device__ __forceinline__ short f2bf(float f) {  // RNE float->bf16 (weights, one-time)
  union { float f; unsigned u; } v; v.f = f;
  unsigned r = v.u + 0x7FFFu + ((v.u >> 16) & 1u);
  return (short)(r >> 16);
}
__device__ __forceinline__ unsigned pk2bf(float a, float b) {  // v_cvt_pk_bf16_f32
  float2 t; t.x = a; t.y = b;
  union { __hip_bfloat162 h; unsigned u; } c;
  c.h = __float22bfloat162_rn(t);
  return c.u;
}

__device__ __forceinline__ s16x8 wfragA(const float* W, int ncols, int row, int col0) {
  const float* p = W + row * ncols + col0;
  s16x8 r;
#pragma unroll
  for (int i = 0; i < 8; ++i) r[i] = f2bf(p[i]);
  return r;
}

__global__ __launch_bounds__(192, 2) void rnn3_pipe(
    const float* __restrict__ x,
    const float* __restrict__ Wih0, const float* __restrict__ Whh0,
    const float* __restrict__ bih0, const float* __restrict__ bhh0,
    const float* __restrict__ Wih1, const float* __restrict__ Whh1,
    const float* __restrict__ bih1, const float* __restrict__ bhh1,
    const float* __restrict__ Wih2, const float* __restrict__ Whh2,
    const float* __restrict__ bih2, const float* __restrict__ bhh2,
    const float* __restrict__ Wfc, const float* __restrict__ bfc,
    float* __restrict__ out)
{
  __shared__ __align__(16) short hb[3][2][16][72];  // [layer][t&1][batch][j], 13824 B

  const int tid = threadIdx.x;
  const int wv  = tid >> 6;       // 0..2 == layer this wave owns
  const int ln  = tid & 63;
  const int q   = ln >> 4;
  const int m15 = ln & 15;
  const int bbase = (int)blockIdx.x * 16;

  // ---------- this wave's layer parameters ----------
  const float* Wih = (wv == 0) ? Wih0 : (wv == 1) ? Wih1 : Wih2;
  const float* Whh = (wv == 0) ? Whh0 : (wv == 1) ? Whh1 : Whh2;
  const float* bi  = (wv == 0) ? bih0 : (wv == 1) ? bih1 : bih2;
  const float* bh  = (wv == 0) ? bhh0 : (wv == 1) ? bhh1 : bhh2;
  const int kin = (wv == 0) ? 32 : 64;   // input width (x vs h)

  // ---------- weight A-fragments, all 4 j-tiles of this layer (VGPR-resident) ----
  s16x8 wi0[4], wi1[4], wh0[4], wh1[4];
  const s16x8 z8 = {0, 0, 0, 0, 0, 0, 0, 0};
#pragma unroll
  for (int tile = 0; tile < 4; ++tile) {
    const int row = 16 * tile + m15;
    wi0[tile] = wfragA(Wih, kin, row, 8 * q);
    wi1[tile] = wv ? wfragA(Wih, 64, row, 32 + 8 * q) : z8;   // layer 0: K=32 only
    wh0[tile] = wfragA(Whh, 64, row, 8 * q);
    wh1[tile] = wfragA(Whh, 64, row, 32 + 8 * q);
  }

  // ---------- biases pre-scaled by 2*log2(e); lane's j = 16*tile + 4*q + r ------
  float bsc[4][4];
#pragma unroll
  for (int tile = 0; tile < 4; ++tile)
#pragma unroll
    for (int r = 0; r < 4; ++r) {
      const int j = 16 * tile + 4 * q + r;
      bsc[tile][r] = (bi[j] + bh[j]) * K2LOG2E;
    }

  const fx4 z4 = {0.f, 0.f, 0.f, 0.f};
  s16x8 r0 = z8, r1 = z8;          // own recurrent state h_wv(t-1), B-layout

  // wave 0's x source: lane reads x[bbase+m15][t][8q..8q+7]; prefetched 1 tick ahead
  const float* xr = x + (size_t)(bbase + m15) * (80 * 32) + 8 * q;
  fx4 xc0 = {0,0,0,0}, xc1 = {0,0,0,0};
  if (wv == 0) { xc0 = *(const fx4*)(xr); xc1 = *(const fx4*)(xr + 4); }

  float hk[4][4];                  // tanh outputs of the last computed tick (FC use)

  for (int tau = 0; tau < 82; ++tau) {
    const int lt = tau - wv;                 // this wave's time step
    if (0 <= lt && lt < 80) {                // wave-uniform guard
      const int p = lt & 1;
      // ---- input B-frags ----
      s16x8 in0, in1;
      if (wv) {
        const short* up = &hb[wv - 1][p][m15][8 * q];   // h_{wv-1}(lt), upstream
        in0 = *(const s16x8*)(up);
        in1 = *(const s16x8*)(up + 32);
      } else {
        union { unsigned u[4]; s16x8 v; } xp;
        xp.u[0] = pk2bf(xc0[0], xc0[1]); xp.u[1] = pk2bf(xc0[2], xc0[3]);
        xp.u[2] = pk2bf(xc1[0], xc1[1]); xp.u[3] = pk2bf(xc1[2], xc1[3]);
        in0 = xp.v; in1 = z8;
        const int tn = (lt < 79) ? lt + 1 : 79;         // prefetch x(t+1)
        xc0 = *(const fx4*)(xr + tn * 32);
        xc1 = *(const fx4*)(xr + tn * 32 + 4);
      }
      // ---- MFMA: Whh*rec first (registers ready) to hide the upstream ds_read ----
      fx4 acc[4];
#pragma unroll
      for (int tile = 0; tile < 4; ++tile) acc[tile] = MFMA16(wh0[tile], r0, z4);
#pragma unroll
      for (int tile = 0; tile < 4; ++tile) acc[tile] = MFMA16(wh1[tile], r1, acc[tile]);
#pragma unroll
      for (int tile = 0; tile < 4; ++tile) acc[tile] = MFMA16(wi0[tile], in0, acc[tile]);
      if (wv) {
#pragma unroll
        for (int tile = 0; tile < 4; ++tile) acc[tile] = MFMA16(wi1[tile], in1, acc[tile]);
      }
      // ---- tanh + pack + store h_wv(lt) ----
      short* wb = &hb[wv][p][m15][4 * q];
#pragma unroll
      for (int tile = 0; tile < 4; ++tile) {
        float h[4];
#pragma unroll
        for (int r = 0; r < 4; ++r) {
          float e = EXP2F(__builtin_fmaf(acc[tile][r], K2LOG2E, bsc[tile][r]));
          h[r] = __builtin_fmaf(-2.f, RCPF(e + 1.f), 1.f);
          hk[tile][r] = h[r];
        }
        union { unsigned u[2]; s16x4 v; } pk;
        pk.u[0] = pk2bf(h[0], h[1]);
        pk.u[1] = pk2bf(h[2], h[3]);
        *(s16x4*)(wb + 16 * tile) = pk.v;
      }
      // ---- own-recurrence transpose readback (pre-barrier; same-wave RAW safe) ----
      const short* ow = &hb[wv][p][m15][8 * q];
      r0 = *(const s16x8*)(ow);
      r1 = *(const s16x8*)(ow + 32);
    }
    __syncthreads();                         // ONE barrier per tick
  }

  // ---------- FC head: wave 2's last tick produced h2(79) in hk ----------
  if (wv == 2) {
    float s = 0.f;
#pragma unroll
    for (int tile = 0; tile < 4; ++tile)
#pragma unroll
      for (int r = 0; r < 4; ++r)
        s += hk[tile][r] * Wfc[16 * tile + 4 * q + r];
    s += __shfl_xor(s, 16, 64);
    s += __shfl_xor(s, 32, 64);
    if (ln < 16) out[bbase + ln] = s + bfc[0];
  }
}

extern "C" void kernel_launch(void* const* d_in, const int* in_sizes, int n_in,
                              void* d_out, int out_size, void* d_ws, size_t ws_size,
                              hipStream_t stream) {
  const float* x    = (const float*)d_in[0];
  const float* Wih0 = (const float*)d_in[1];
  const float* Whh0 = (const float*)d_in[2];
  const float* bih0 = (const float*)d_in[3];
  const float* bhh0 = (const float*)d_in[4];
  const float* Wih1 = (const float*)d_in[5];
  const float* Whh1 = (const float*)d_in[6];
  const float* bih1 = (const float*)d_in[7];
  const float* bhh1 = (const float*)d_in[8];
  const float* Wih2 = (const float*)d_in[9];
  const float* Whh2 = (const float*)d_in[10];
  const float* bih2 = (const float*)d_in[11];
  const float* bhh2 = (const float*)d_in[12];
  const float* Wfc  = (const float*)d_in[13];
  const float* bfc  = (const float*)d_in[14];

  // 512 blocks x 192 thr (3 waves = 3 pipelined layers), 16 batch rows per block.
  rnn3_pipe<<<dim3(512), dim3(192), 0, stream>>>(
      x, Wih0, Whh0, bih0, bhh0, Wih1, Whh1, bih1, bhh1,
      Wih2, Whh2, bih2, bhh2, Wfc, bfc, (float*)d_out);
}